// Round 1
// baseline (809.291 us; speedup 1.0000x reference)
//
#include <hip/hip_runtime.h>
#include <math.h>

// Problem constants (match reference)
#define UU 500000
#define II 500000
#define DD 64
#define KK 32
#define BB 8192
#define NNEG 128

__device__ __forceinline__ float softplus_f(float x) {
    // stable softplus: max(x,0) + log1p(exp(-|x|))
    return fmaxf(x, 0.0f) + log1pf(expf(-fabsf(x)));
}

__device__ __forceinline__ float waveReduceSum(float v) {
#pragma unroll
    for (int off = 32; off > 0; off >>= 1) v += __shfl_xor(v, off, 64);
    return v;
}

// ---------------- norm: sum of squares over all params ----------------
__global__ __launch_bounds__(256) void norm_kernel(
    const float* __restrict__ user_emb, const float* __restrict__ item_emb,
    const float* __restrict__ mse_u_w, const float* __restrict__ mse_u_b,
    const float* __restrict__ mse_i_w, const float* __restrict__ mse_i_b,
    const float* __restrict__ fc1_w1, const float* __restrict__ fc1_b1,
    const float* __restrict__ fc1_w2, const float* __restrict__ fc1_b2,
    float* __restrict__ acc)
{
    const size_t tid = (size_t)blockIdx.x * blockDim.x + threadIdx.x;
    const size_t stride = (size_t)gridDim.x * blockDim.x;
    float s = 0.0f;
    const size_t n4 = (size_t)UU * DD / 4;  // 8M float4 per big table
    const float4* a = (const float4*)user_emb;
    for (size_t i = tid; i < n4; i += stride) {
        float4 v = a[i];
        s += v.x * v.x + v.y * v.y + v.z * v.z + v.w * v.w;
    }
    const float4* c = (const float4*)item_emb;
    for (size_t i = tid; i < n4; i += stride) {
        float4 v = c[i];
        s += v.x * v.x + v.y * v.y + v.z * v.z + v.w * v.w;
    }
    // small params
    for (size_t i = tid; i < (size_t)DD * DD; i += stride) {
        s += mse_u_w[i] * mse_u_w[i] + mse_i_w[i] * mse_i_w[i];
    }
    for (size_t i = tid; i < (size_t)DD * 2 * DD; i += stride) {
        s += fc1_w1[i] * fc1_w1[i];
    }
    for (size_t i = tid; i < (size_t)DD; i += stride) {
        s += mse_u_b[i] * mse_u_b[i] + mse_i_b[i] * mse_i_b[i]
           + fc1_b1[i] * fc1_b1[i] + fc1_w2[i] * fc1_w2[i];
    }
    if (tid == 0) s += fc1_b2[0] * fc1_b2[0];

    s = waveReduceSum(s);
    __shared__ float ls[4];
    if ((threadIdx.x & 63) == 0) ls[threadIdx.x >> 6] = s;
    __syncthreads();
    if (threadIdx.x == 0)
        atomicAdd(&acc[2], ls[0] + ls[1] + ls[2] + ls[3]);
}

// ---------------- main per-sample kernel: loss_L + loss_I ----------------
// One wave per b. lane = embedding dim index.
__global__ __launch_bounds__(256) void main_kernel(
    const int* __restrict__ users, const int* __restrict__ pos_items,
    const int* __restrict__ neg_items,
    const float* __restrict__ user_emb, const float* __restrict__ item_emb,
    const float* __restrict__ beta_uD, const float* __restrict__ beta_iD,
    const int* __restrict__ ii_nbr, const float* __restrict__ ii_con,
    float* __restrict__ acc)
{
    const int wave = threadIdx.x >> 6;
    const int lane = threadIdx.x & 63;
    const int b = blockIdx.x * 4 + wave;

    const int u_idx = users[b];
    const int p_idx = pos_items[b];
    const float u = user_emb[(size_t)u_idx * DD + lane];
    const float p = item_emb[(size_t)p_idx * DD + lane];
    const float bu = beta_uD[u_idx];

    // preload neg indices + their beta gathers (2 per lane), broadcast later
    const int i0 = neg_items[(size_t)b * NNEG + lane];
    const int i1 = neg_items[(size_t)b * NNEG + 64 + lane];
    const float bn0 = beta_iD[i0];
    const float bn1 = beta_iD[i1];

    const float pos_dot = waveReduceSum(u * p);
    const float pos_w = 1e-6f + 1.0f * bu * beta_iD[p_idx];
    const float pos_loss = pos_w * softplus_f(-pos_dot);

    float neg_sum = 0.0f;
#pragma unroll 4
    for (int n = 0; n < 64; ++n) {
        const int idx = __shfl(i0, n, 64);
        const float v = item_emb[(size_t)idx * DD + lane];
        const float dot = waveReduceSum(u * v);
        const float bi = __shfl(bn0, n, 64);
        neg_sum += (1e-6f + 1.0f * bu * bi) * softplus_f(dot);
    }
#pragma unroll 4
    for (int n = 0; n < 64; ++n) {
        const int idx = __shfl(i1, n, 64);
        const float v = item_emb[(size_t)idx * DD + lane];
        const float dot = waveReduceSum(u * v);
        const float bi = __shfl(bn1, n, 64);
        neg_sum += (1e-6f + 1.0f * bu * bi) * softplus_f(dot);
    }

    // loss_I: neighbors of pos item
    int nb = 0;
    float sim = 0.0f;
    if (lane < KK) {
        nb = ii_nbr[(size_t)p_idx * KK + lane];
        sim = ii_con[(size_t)p_idx * KK + lane];
    }
    float i_sum = 0.0f;
#pragma unroll 4
    for (int k = 0; k < KK; ++k) {
        const int idx = __shfl(nb, k, 64);
        const float v = item_emb[(size_t)idx * DD + lane];
        const float dot = waveReduceSum(u * v);
        const float sk = __shfl(sim, k, 64);
        i_sum += sk * softplus_f(-dot);
    }

    if (lane == 0) {
        atomicAdd(&acc[0], pos_loss + 200.0f * (neg_sum * (1.0f / NNEG)));
        atomicAdd(&acc[1], i_sum);
    }
}

// ---------------- mse kernel ----------------
__global__ __launch_bounds__(256) void mse_kernel(
    const int* __restrict__ users, const int* __restrict__ pos_items,
    const float* __restrict__ rpkms,
    const float* __restrict__ user_emb, const float* __restrict__ item_emb,
    const float* __restrict__ mse_u_w, const float* __restrict__ mse_u_b,
    const float* __restrict__ mse_i_w, const float* __restrict__ mse_i_b,
    float* __restrict__ acc)
{
    __shared__ float sWu[DD * (DD + 1)];   // padded stride 65 -> 2-way bank alias (free)
    __shared__ float sWi[DD * (DD + 1)];
    __shared__ float sBu[DD], sBi[DD];
    __shared__ float sUe[4][DD], sPe[4][DD];

    for (int i = threadIdx.x; i < DD * DD; i += blockDim.x) {
        const int r = i >> 6, c = i & 63;
        sWu[r * (DD + 1) + c] = mse_u_w[i];
        sWi[r * (DD + 1) + c] = mse_i_w[i];
    }
    if (threadIdx.x < DD) {
        sBu[threadIdx.x] = mse_u_b[threadIdx.x];
        sBi[threadIdx.x] = mse_i_b[threadIdx.x];
    }

    const int wave = threadIdx.x >> 6;
    const int lane = threadIdx.x & 63;
    const int b = blockIdx.x * 4 + wave;
    sUe[wave][lane] = user_emb[(size_t)users[b] * DD + lane];
    sPe[wave][lane] = item_emb[(size_t)pos_items[b] * DD + lane];
    __syncthreads();

    float fu = sBu[lane];
    float fi = sBi[lane];
#pragma unroll 8
    for (int d = 0; d < DD; ++d) {
        fu += sUe[wave][d] * sWu[lane * (DD + 1) + d];
        fi += sPe[wave][d] * sWi[lane * (DD + 1) + d];
    }
    const float pred = waveReduceSum(fu * fi);
    if (lane == 0) {
        const float diff = pred - rpkms[b];
        atomicAdd(&acc[3], diff * diff);
    }
}

// ---------------- finalize ----------------
__global__ void finalize_kernel(const float* __restrict__ acc, float* __restrict__ out)
{
    if (threadIdx.x == 0) {
        const float loss_L = acc[0] / (float)BB;
        const float loss_I = 2.5f * acc[1] / (float)(BB * KK);
        const float mse    = acc[3] / (float)BB;
        const float norm   = 1e-4f * 0.5f * acc[2];
        const float total  = loss_L + norm + loss_I + mse;
        out[0] = total;
        out[1] = loss_L;
        out[2] = loss_I;
        out[3] = 0.0f;
        out[4] = mse;
        out[5] = norm;
    }
}

extern "C" void kernel_launch(void* const* d_in, const int* in_sizes, int n_in,
                              void* d_out, int out_size, void* d_ws, size_t ws_size,
                              hipStream_t stream)
{
    const int*   users      = (const int*)  d_in[0];
    const int*   pos_items  = (const int*)  d_in[1];
    const int*   neg_items  = (const int*)  d_in[2];
    const float* rpkms      = (const float*)d_in[3];
    const float* user_emb   = (const float*)d_in[4];
    const float* item_emb   = (const float*)d_in[5];
    const float* beta_uD    = (const float*)d_in[6];
    const float* beta_iD    = (const float*)d_in[7];
    const int*   ii_nbr     = (const int*)  d_in[8];
    const float* ii_con     = (const float*)d_in[9];
    const float* mse_u_w    = (const float*)d_in[10];
    const float* mse_u_b    = (const float*)d_in[11];
    const float* mse_i_w    = (const float*)d_in[12];
    const float* mse_i_b    = (const float*)d_in[13];
    const float* fc1_w1     = (const float*)d_in[14];
    const float* fc1_b1     = (const float*)d_in[15];
    const float* fc1_w2     = (const float*)d_in[16];
    const float* fc1_b2     = (const float*)d_in[17];

    float* acc = (float*)d_ws;   // acc[0]=loss_L sum, acc[1]=loss_I sum, acc[2]=norm sum, acc[3]=mse sum
    hipMemsetAsync(d_ws, 0, 4 * sizeof(float), stream);

    // stream item_emb LAST so it is L3-resident for the gather kernel
    norm_kernel<<<2048, 256, 0, stream>>>(user_emb, item_emb,
                                          mse_u_w, mse_u_b, mse_i_w, mse_i_b,
                                          fc1_w1, fc1_b1, fc1_w2, fc1_b2, acc);

    main_kernel<<<BB / 4, 256, 0, stream>>>(users, pos_items, neg_items,
                                            user_emb, item_emb, beta_uD, beta_iD,
                                            ii_nbr, ii_con, acc);

    mse_kernel<<<BB / 4, 256, 0, stream>>>(users, pos_items, rpkms,
                                           user_emb, item_emb,
                                           mse_u_w, mse_u_b, mse_i_w, mse_i_b, acc);

    finalize_kernel<<<1, 64, 0, stream>>>(acc, (float*)d_out);
}

// Round 2
// 554.657 us; speedup vs baseline: 1.4591x; 1.4591x over previous
//
#include <hip/hip_runtime.h>
#include <math.h>

// Problem constants (match reference)
#define UU 500000
#define II 500000
#define DD 64
#define KK 32
#define BB 8192
#define NNEG 128

__device__ __forceinline__ float softplus_f(float x) {
    // stable softplus: max(x,0) + log1p(exp(-|x|))
    return fmaxf(x, 0.0f) + log1pf(expf(-fabsf(x)));
}

__device__ __forceinline__ float waveReduceSum(float v) {
#pragma unroll
    for (int off = 32; off > 0; off >>= 1) v += __shfl_xor(v, off, 64);
    return v;
}

// ---------------------------------------------------------------------------
// Fused kernel: norm (streaming) + loss_L + loss_I (gather).
// Grid: 2048 blocks x 256 threads = 8192 waves; one wave per sample b.
// Gather layout: 4 lanes per item, 16 items per pass. Lane 4i+q reads the
// float4 at byte offset j*64 + q*16 of item i's row at iteration j, so each
// instruction touches 16 contiguous 64B lines (ideal gather coalescing).
// u is broadcast from registers via __shfl (bpermute).
// ---------------------------------------------------------------------------
__global__ __launch_bounds__(256) void fused_kernel(
    const int* __restrict__ users, const int* __restrict__ pos_items,
    const int* __restrict__ neg_items,
    const float* __restrict__ user_emb, const float* __restrict__ item_emb,
    const float* __restrict__ beta_uD, const float* __restrict__ beta_iD,
    const int* __restrict__ ii_nbr, const float* __restrict__ ii_con,
    const float* __restrict__ mse_u_w, const float* __restrict__ mse_u_b,
    const float* __restrict__ mse_i_w, const float* __restrict__ mse_i_b,
    const float* __restrict__ fc1_w1, const float* __restrict__ fc1_b1,
    const float* __restrict__ fc1_w2, const float* __restrict__ fc1_b2,
    float* __restrict__ acc)
{
    float norm_s = 0.f, accL = 0.f, accI = 0.f;

    // ---------------- norm phase: pure bandwidth streaming ----------------
    {
        const size_t tid    = (size_t)blockIdx.x * blockDim.x + threadIdx.x;
        const size_t stride = (size_t)gridDim.x * blockDim.x;
        const size_t n4 = (size_t)UU * DD / 4;  // 8M float4 per table
        const float4* a = (const float4*)user_emb;
        for (size_t i = tid; i < n4; i += stride) {
            float4 v = a[i];
            norm_s += v.x * v.x + v.y * v.y + v.z * v.z + v.w * v.w;
        }
        const float4* c = (const float4*)item_emb;   // last: leaves item_emb L3-warm
        for (size_t i = tid; i < n4; i += stride) {
            float4 v = c[i];
            norm_s += v.x * v.x + v.y * v.y + v.z * v.z + v.w * v.w;
        }
        for (size_t i = tid; i < (size_t)DD * DD; i += stride)
            norm_s += mse_u_w[i] * mse_u_w[i] + mse_i_w[i] * mse_i_w[i];
        for (size_t i = tid; i < (size_t)DD * 2 * DD; i += stride)
            norm_s += fc1_w1[i] * fc1_w1[i];
        for (size_t i = tid; i < (size_t)DD; i += stride)
            norm_s += mse_u_b[i] * mse_u_b[i] + mse_i_b[i] * mse_i_b[i]
                    + fc1_b1[i] * fc1_b1[i] + fc1_w2[i] * fc1_w2[i];
        if (tid == 0) norm_s += fc1_b2[0] * fc1_b2[0];
    }

    // ---------------- gather phase: one wave per b ----------------
    const int wave = threadIdx.x >> 6;
    const int lane = threadIdx.x & 63;
    const int b = blockIdx.x * 4 + wave;

    const int u_idx = users[b];
    const int p_idx = pos_items[b];
    const float u_reg = user_emb[(size_t)u_idx * DD + lane];  // lane l holds u[l]
    const float bu = beta_uD[u_idx];

    // pos term (one-off wave reduce is fine)
    {
        const float p = item_emb[(size_t)p_idx * DD + lane];
        const float pos_dot = waveReduceSum(u_reg * p);
        if (lane == 0)
            accL += (1e-6f + bu * beta_iD[p_idx]) * softplus_f(-pos_dot);
    }

    // preload neg indices + beta gathers (lane l holds items l and l+64)
    const int i0 = neg_items[(size_t)b * NNEG + lane];
    const int i1 = neg_items[(size_t)b * NNEG + 64 + lane];
    const float bn0 = beta_iD[i0];
    const float bn1 = beta_iD[i1];

    const int q  = lane & 3;   // lane's quarter-line within its item
    const int li = lane >> 2;  // local item index within pass (0..15)
    const float negscale4 = 0.25f * (200.0f / (float)NNEG);  // 0.25: 4 lanes redundant

    // ---- 128 negatives: 8 passes of 16 items ----
#pragma unroll 2
    for (int p = 0; p < 8; ++p) {
        const int n = p * 16 + li;                 // global neg index 0..127
        int idx; float bi;
        if (p < 4) { idx = __shfl(i0, n, 64);      bi = __shfl(bn0, n, 64); }
        else       { idx = __shfl(i1, n - 64, 64); bi = __shfl(bn1, n - 64, 64); }
        const float* row = item_emb + (size_t)idx * DD;
        float dot = 0.f;
#pragma unroll
        for (int j = 0; j < 4; ++j) {
            const float4 v = *(const float4*)(row + j * 16 + q * 4);
            const int base = j * 16 + q * 4;
            dot = fmaf(v.x, __shfl(u_reg, base + 0, 64), dot);
            dot = fmaf(v.y, __shfl(u_reg, base + 1, 64), dot);
            dot = fmaf(v.z, __shfl(u_reg, base + 2, 64), dot);
            dot = fmaf(v.w, __shfl(u_reg, base + 3, 64), dot);
        }
        dot += __shfl_xor(dot, 1, 64);
        dot += __shfl_xor(dot, 2, 64);             // all 4 lanes hold item dot
        accL += negscale4 * (1e-6f + bu * bi) * softplus_f(dot);
    }

    // ---- 32 neighbors (loss_I): 2 passes of 16 items ----
    int nbv = 0; float simv = 0.f;
    if (lane < KK) {
        nbv  = ii_nbr[(size_t)p_idx * KK + lane];
        simv = ii_con[(size_t)p_idx * KK + lane];
    }
#pragma unroll
    for (int p = 0; p < 2; ++p) {
        const int n = p * 16 + li;                 // 0..31, sourced from lanes <32
        const int idx  = __shfl(nbv, n, 64);
        const float sk = __shfl(simv, n, 64);
        const float* row = item_emb + (size_t)idx * DD;
        float dot = 0.f;
#pragma unroll
        for (int j = 0; j < 4; ++j) {
            const float4 v = *(const float4*)(row + j * 16 + q * 4);
            const int base = j * 16 + q * 4;
            dot = fmaf(v.x, __shfl(u_reg, base + 0, 64), dot);
            dot = fmaf(v.y, __shfl(u_reg, base + 1, 64), dot);
            dot = fmaf(v.z, __shfl(u_reg, base + 2, 64), dot);
            dot = fmaf(v.w, __shfl(u_reg, base + 3, 64), dot);
        }
        dot += __shfl_xor(dot, 1, 64);
        dot += __shfl_xor(dot, 2, 64);
        accI += 0.25f * sk * softplus_f(-dot);
    }

    // ---------------- block reduce + one atomic per block ----------------
    norm_s = waveReduceSum(norm_s);
    accL   = waveReduceSum(accL);
    accI   = waveReduceSum(accI);
    __shared__ float red[3][4];
    if (lane == 0) { red[0][wave] = norm_s; red[1][wave] = accL; red[2][wave] = accI; }
    __syncthreads();
    if (threadIdx.x == 0) {
        atomicAdd(&acc[0], red[1][0] + red[1][1] + red[1][2] + red[1][3]);
        atomicAdd(&acc[1], red[2][0] + red[2][1] + red[2][2] + red[2][3]);
        atomicAdd(&acc[2], red[0][0] + red[0][1] + red[0][2] + red[0][3]);
    }
}

// ---------------- mse kernel ----------------
__global__ __launch_bounds__(256) void mse_kernel(
    const int* __restrict__ users, const int* __restrict__ pos_items,
    const float* __restrict__ rpkms,
    const float* __restrict__ user_emb, const float* __restrict__ item_emb,
    const float* __restrict__ mse_u_w, const float* __restrict__ mse_u_b,
    const float* __restrict__ mse_i_w, const float* __restrict__ mse_i_b,
    float* __restrict__ acc)
{
    __shared__ float sWu[DD * (DD + 1)];   // stride 65 -> 2-way bank alias (free)
    __shared__ float sWi[DD * (DD + 1)];
    __shared__ float sBu[DD], sBi[DD];
    __shared__ float sUe[4][DD], sPe[4][DD];

    for (int i = threadIdx.x; i < DD * DD; i += blockDim.x) {
        const int r = i >> 6, c = i & 63;
        sWu[r * (DD + 1) + c] = mse_u_w[i];
        sWi[r * (DD + 1) + c] = mse_i_w[i];
    }
    if (threadIdx.x < DD) {
        sBu[threadIdx.x] = mse_u_b[threadIdx.x];
        sBi[threadIdx.x] = mse_i_b[threadIdx.x];
    }

    const int wave = threadIdx.x >> 6;
    const int lane = threadIdx.x & 63;
    const int b = blockIdx.x * 4 + wave;
    sUe[wave][lane] = user_emb[(size_t)users[b] * DD + lane];
    sPe[wave][lane] = item_emb[(size_t)pos_items[b] * DD + lane];
    __syncthreads();

    float fu = sBu[lane];
    float fi = sBi[lane];
#pragma unroll 8
    for (int d = 0; d < DD; ++d) {
        fu += sUe[wave][d] * sWu[lane * (DD + 1) + d];
        fi += sPe[wave][d] * sWi[lane * (DD + 1) + d];
    }
    const float pred = waveReduceSum(fu * fi);
    if (lane == 0) {
        const float diff = pred - rpkms[b];
        atomicAdd(&acc[3], diff * diff);
    }
}

// ---------------- finalize ----------------
__global__ void finalize_kernel(const float* __restrict__ acc, float* __restrict__ out)
{
    if (threadIdx.x == 0) {
        const float loss_L = acc[0] / (float)BB;
        const float loss_I = 2.5f * acc[1] / (float)(BB * KK);
        const float mse    = acc[3] / (float)BB;
        const float norm   = 1e-4f * 0.5f * acc[2];
        const float total  = loss_L + norm + loss_I + mse;
        out[0] = total;
        out[1] = loss_L;
        out[2] = loss_I;
        out[3] = 0.0f;
        out[4] = mse;
        out[5] = norm;
    }
}

extern "C" void kernel_launch(void* const* d_in, const int* in_sizes, int n_in,
                              void* d_out, int out_size, void* d_ws, size_t ws_size,
                              hipStream_t stream)
{
    const int*   users      = (const int*)  d_in[0];
    const int*   pos_items  = (const int*)  d_in[1];
    const int*   neg_items  = (const int*)  d_in[2];
    const float* rpkms      = (const float*)d_in[3];
    const float* user_emb   = (const float*)d_in[4];
    const float* item_emb   = (const float*)d_in[5];
    const float* beta_uD    = (const float*)d_in[6];
    const float* beta_iD    = (const float*)d_in[7];
    const int*   ii_nbr     = (const int*)  d_in[8];
    const float* ii_con     = (const float*)d_in[9];
    const float* mse_u_w    = (const float*)d_in[10];
    const float* mse_u_b    = (const float*)d_in[11];
    const float* mse_i_w    = (const float*)d_in[12];
    const float* mse_i_b    = (const float*)d_in[13];
    const float* fc1_w1     = (const float*)d_in[14];
    const float* fc1_b1     = (const float*)d_in[15];
    const float* fc1_w2     = (const float*)d_in[16];
    const float* fc1_b2     = (const float*)d_in[17];

    float* acc = (float*)d_ws;  // [0]=loss_L sum, [1]=loss_I sum, [2]=norm sum, [3]=mse sum
    hipMemsetAsync(d_ws, 0, 4 * sizeof(float), stream);

    fused_kernel<<<BB / 4, 256, 0, stream>>>(users, pos_items, neg_items,
                                             user_emb, item_emb, beta_uD, beta_iD,
                                             ii_nbr, ii_con,
                                             mse_u_w, mse_u_b, mse_i_w, mse_i_b,
                                             fc1_w1, fc1_b1, fc1_w2, fc1_b2, acc);

    mse_kernel<<<BB / 4, 256, 0, stream>>>(users, pos_items, rpkms,
                                           user_emb, item_emb,
                                           mse_u_w, mse_u_b, mse_i_w, mse_i_b, acc);

    finalize_kernel<<<1, 64, 0, stream>>>(acc, (float*)d_out);
}

// Round 3
// 531.451 us; speedup vs baseline: 1.5228x; 1.0437x over previous
//
#include <hip/hip_runtime.h>
#include <math.h>

// Problem constants (match reference)
#define UU 500000
#define II 500000
#define DD 64
#define KK 32
#define BB 8192
#define NNEG 128

#define NORMB 1024          // norm-role blocks (come first in dispatch order)
#define GATHB (BB / 4)      // 2048 gather-role blocks, one wave per sample

typedef float v4f __attribute__((ext_vector_type(4)));

__device__ __forceinline__ float softplus_f(float x) {
    return fmaxf(x, 0.0f) + log1pf(expf(-fabsf(x)));
}

__device__ __forceinline__ float waveReduceSum(float v) {
#pragma unroll
    for (int off = 32; off > 0; off >>= 1) v += __shfl_xor(v, off, 64);
    return v;
}

// ---------------------------------------------------------------------------
// Fused kernel, role-split grid:
//   blocks [0, NORMB)            : stream norm (BW-bound)   — overlaps with
//   blocks [NORMB, NORMB+GATHB)  : gather loss_L/loss_I (latency-bound)
// Gather: 4 lanes per item, 16 items per group, 4 groups batched so 16
// float4 loads are in flight before any consumption.
// ---------------------------------------------------------------------------
__global__ __launch_bounds__(256) void fused_kernel(
    const int* __restrict__ users, const int* __restrict__ pos_items,
    const int* __restrict__ neg_items,
    const float* __restrict__ user_emb, const float* __restrict__ item_emb,
    const float* __restrict__ beta_uD, const float* __restrict__ beta_iD,
    const int* __restrict__ ii_nbr, const float* __restrict__ ii_con,
    const float* __restrict__ mse_u_w, const float* __restrict__ mse_u_b,
    const float* __restrict__ mse_i_w, const float* __restrict__ mse_i_b,
    const float* __restrict__ fc1_w1, const float* __restrict__ fc1_b1,
    const float* __restrict__ fc1_w2, const float* __restrict__ fc1_b2,
    float* __restrict__ acc)
{
    const int wave = threadIdx.x >> 6;
    const int lane = threadIdx.x & 63;
    __shared__ float red[4];

    if (blockIdx.x < NORMB) {
        // ---------------- norm role: pure streaming ----------------
        const size_t tid = (size_t)blockIdx.x * blockDim.x + threadIdx.x;
        const size_t st  = (size_t)NORMB * 256;
        const size_t n4  = (size_t)UU * DD / 4;   // 8M float4 per table
        float s0 = 0.f, s1 = 0.f, s2 = 0.f, s3 = 0.f;

        // user_emb: non-temporal (don't evict item_emb from L3)
        {
            const v4f* a = (const v4f*)user_emb;
            size_t i = tid;
            for (; i + 3 * st < n4; i += 4 * st) {
                v4f x0 = __builtin_nontemporal_load(&a[i]);
                v4f x1 = __builtin_nontemporal_load(&a[i + st]);
                v4f x2 = __builtin_nontemporal_load(&a[i + 2 * st]);
                v4f x3 = __builtin_nontemporal_load(&a[i + 3 * st]);
                s0 += x0.x*x0.x + x0.y*x0.y + x0.z*x0.z + x0.w*x0.w;
                s1 += x1.x*x1.x + x1.y*x1.y + x1.z*x1.z + x1.w*x1.w;
                s2 += x2.x*x2.x + x2.y*x2.y + x2.z*x2.z + x2.w*x2.w;
                s3 += x3.x*x3.x + x3.y*x3.y + x3.z*x3.z + x3.w*x3.w;
            }
            for (; i < n4; i += st) {
                v4f x = __builtin_nontemporal_load(&a[i]);
                s0 += x.x*x.x + x.y*x.y + x.z*x.z + x.w*x.w;
            }
        }
        // item_emb: normal loads (keep L3-warm for gathers)
        {
            const v4f* c = (const v4f*)item_emb;
            size_t i = tid;
            for (; i + 3 * st < n4; i += 4 * st) {
                v4f x0 = c[i];
                v4f x1 = c[i + st];
                v4f x2 = c[i + 2 * st];
                v4f x3 = c[i + 3 * st];
                s0 += x0.x*x0.x + x0.y*x0.y + x0.z*x0.z + x0.w*x0.w;
                s1 += x1.x*x1.x + x1.y*x1.y + x1.z*x1.z + x1.w*x1.w;
                s2 += x2.x*x2.x + x2.y*x2.y + x2.z*x2.z + x2.w*x2.w;
                s3 += x3.x*x3.x + x3.y*x3.y + x3.z*x3.z + x3.w*x3.w;
            }
            for (; i < n4; i += st) {
                v4f x = c[i];
                s0 += x.x*x.x + x.y*x.y + x.z*x.z + x.w*x.w;
            }
        }
        float s = (s0 + s1) + (s2 + s3);
        // small params
        for (size_t i = tid; i < (size_t)DD * DD; i += st)
            s += mse_u_w[i] * mse_u_w[i] + mse_i_w[i] * mse_i_w[i];
        for (size_t i = tid; i < (size_t)DD * 2 * DD; i += st)
            s += fc1_w1[i] * fc1_w1[i];
        for (size_t i = tid; i < (size_t)DD; i += st)
            s += mse_u_b[i] * mse_u_b[i] + mse_i_b[i] * mse_i_b[i]
               + fc1_b1[i] * fc1_b1[i] + fc1_w2[i] * fc1_w2[i];
        if (tid == 0) s += fc1_b2[0] * fc1_b2[0];

        s = waveReduceSum(s);
        if (lane == 0) red[wave] = s;
        __syncthreads();
        if (threadIdx.x == 0)
            atomicAdd(&acc[2], red[0] + red[1] + red[2] + red[3]);
        return;
    }

    // ---------------- gather role: one wave per sample b ----------------
    const int b = (blockIdx.x - NORMB) * 4 + wave;
    float accL = 0.f, accI = 0.f;

    const int u_idx = users[b];
    const int p_idx = pos_items[b];
    const float u_reg = user_emb[(size_t)u_idx * DD + lane];  // lane l holds u[l]
    const float bu = beta_uD[u_idx];

    // wave-local copy of u row -> each lane pulls its 16 needed elements
    __shared__ float sU[4][DD];
    sU[wave][lane] = u_reg;        // wave-synchronous, no barrier needed

    const int q  = lane & 3;       // quarter-line within item
    const int li = lane >> 2;      // local item within 16-item group

    float4 uv[4];
#pragma unroll
    for (int j = 0; j < 4; ++j)
        uv[j] = *(const float4*)&sU[wave][j * 16 + q * 4];

    // pos term
    {
        const float p = item_emb[(size_t)p_idx * DD + lane];
        const float pos_dot = waveReduceSum(u_reg * p);
        if (lane == 0)
            accL += (1e-6f + bu * beta_iD[p_idx]) * softplus_f(-pos_dot);
    }

    // preload neg indices + beta gathers (lane l holds items l and l+64)
    const int i0 = neg_items[(size_t)b * NNEG + lane];
    const int i1 = neg_items[(size_t)b * NNEG + 64 + lane];
    const float bn0 = beta_iD[i0];
    const float bn1 = beta_iD[i1];

    const float negscale4 = 0.25f * (200.0f / (float)NNEG);  // 4 lanes redundant

    // ---- 128 negatives: 2 mega-batches of 64 items (4 groups x 16) ----
#pragma unroll
    for (int g = 0; g < 2; ++g) {
        const int   srcI = g ? i1 : i0;
        const float srcB = g ? bn1 : bn0;
        float4 vb[4][4];
        float  bi4[4];
        // issue: 16 independent float4 loads in flight
#pragma unroll
        for (int t = 0; t < 4; ++t) {
            const int n = t * 16 + li;
            const int idx = __shfl(srcI, n, 64);
            bi4[t] = __shfl(srcB, n, 64);
            const float* row = item_emb + (size_t)idx * DD + q * 4;
#pragma unroll
            for (int j = 0; j < 4; ++j)
                vb[t][j] = *(const float4*)(row + j * 16);
        }
        // consume
#pragma unroll
        for (int t = 0; t < 4; ++t) {
            float dot = 0.f;
#pragma unroll
            for (int j = 0; j < 4; ++j) {
                dot = fmaf(vb[t][j].x, uv[j].x, dot);
                dot = fmaf(vb[t][j].y, uv[j].y, dot);
                dot = fmaf(vb[t][j].z, uv[j].z, dot);
                dot = fmaf(vb[t][j].w, uv[j].w, dot);
            }
            dot += __shfl_xor(dot, 1, 64);
            dot += __shfl_xor(dot, 2, 64);
            accL += negscale4 * (1e-6f + bu * bi4[t]) * softplus_f(dot);
        }
    }

    // ---- 32 neighbors (loss_I): one batch of 2 groups ----
    int nbv = 0; float simv = 0.f;
    if (lane < KK) {
        nbv  = ii_nbr[(size_t)p_idx * KK + lane];
        simv = ii_con[(size_t)p_idx * KK + lane];
    }
    {
        float4 vb[2][4];
        float  sk2[2];
#pragma unroll
        for (int t = 0; t < 2; ++t) {
            const int n = t * 16 + li;
            const int idx = __shfl(nbv, n, 64);
            sk2[t] = __shfl(simv, n, 64);
            const float* row = item_emb + (size_t)idx * DD + q * 4;
#pragma unroll
            for (int j = 0; j < 4; ++j)
                vb[t][j] = *(const float4*)(row + j * 16);
        }
#pragma unroll
        for (int t = 0; t < 2; ++t) {
            float dot = 0.f;
#pragma unroll
            for (int j = 0; j < 4; ++j) {
                dot = fmaf(vb[t][j].x, uv[j].x, dot);
                dot = fmaf(vb[t][j].y, uv[j].y, dot);
                dot = fmaf(vb[t][j].z, uv[j].z, dot);
                dot = fmaf(vb[t][j].w, uv[j].w, dot);
            }
            dot += __shfl_xor(dot, 1, 64);
            dot += __shfl_xor(dot, 2, 64);
            accI += 0.25f * sk2[t] * softplus_f(-dot);
        }
    }

    // ---------------- block reduce + one atomic per block ----------------
    accL = waveReduceSum(accL);
    accI = waveReduceSum(accI);
    __shared__ float redL[4], redI[4];
    if (lane == 0) { redL[wave] = accL; redI[wave] = accI; }
    __syncthreads();
    if (threadIdx.x == 0) {
        atomicAdd(&acc[0], redL[0] + redL[1] + redL[2] + redL[3]);
        atomicAdd(&acc[1], redI[0] + redI[1] + redI[2] + redI[3]);
    }
}

// ---------------- mse kernel ----------------
__global__ __launch_bounds__(256) void mse_kernel(
    const int* __restrict__ users, const int* __restrict__ pos_items,
    const float* __restrict__ rpkms,
    const float* __restrict__ user_emb, const float* __restrict__ item_emb,
    const float* __restrict__ mse_u_w, const float* __restrict__ mse_u_b,
    const float* __restrict__ mse_i_w, const float* __restrict__ mse_i_b,
    float* __restrict__ acc)
{
    __shared__ float sWu[DD * (DD + 1)];   // stride 65 -> 2-way bank alias (free)
    __shared__ float sWi[DD * (DD + 1)];
    __shared__ float sBu[DD], sBi[DD];
    __shared__ float sUe[4][DD], sPe[4][DD];

    for (int i = threadIdx.x; i < DD * DD; i += blockDim.x) {
        const int r = i >> 6, c = i & 63;
        sWu[r * (DD + 1) + c] = mse_u_w[i];
        sWi[r * (DD + 1) + c] = mse_i_w[i];
    }
    if (threadIdx.x < DD) {
        sBu[threadIdx.x] = mse_u_b[threadIdx.x];
        sBi[threadIdx.x] = mse_i_b[threadIdx.x];
    }

    const int wave = threadIdx.x >> 6;
    const int lane = threadIdx.x & 63;
    const int b = blockIdx.x * 4 + wave;
    sUe[wave][lane] = user_emb[(size_t)users[b] * DD + lane];
    sPe[wave][lane] = item_emb[(size_t)pos_items[b] * DD + lane];
    __syncthreads();

    float fu = sBu[lane];
    float fi = sBi[lane];
#pragma unroll 8
    for (int d = 0; d < DD; ++d) {
        fu += sUe[wave][d] * sWu[lane * (DD + 1) + d];
        fi += sPe[wave][d] * sWi[lane * (DD + 1) + d];
    }
    const float pred = waveReduceSum(fu * fi);
    if (lane == 0) {
        const float diff = pred - rpkms[b];
        atomicAdd(&acc[3], diff * diff);
    }
}

// ---------------- finalize ----------------
__global__ void finalize_kernel(const float* __restrict__ acc, float* __restrict__ out)
{
    if (threadIdx.x == 0) {
        const float loss_L = acc[0] / (float)BB;
        const float loss_I = 2.5f * acc[1] / (float)(BB * KK);
        const float mse    = acc[3] / (float)BB;
        const float norm   = 1e-4f * 0.5f * acc[2];
        const float total  = loss_L + norm + loss_I + mse;
        out[0] = total;
        out[1] = loss_L;
        out[2] = loss_I;
        out[3] = 0.0f;
        out[4] = mse;
        out[5] = norm;
    }
}

extern "C" void kernel_launch(void* const* d_in, const int* in_sizes, int n_in,
                              void* d_out, int out_size, void* d_ws, size_t ws_size,
                              hipStream_t stream)
{
    const int*   users      = (const int*)  d_in[0];
    const int*   pos_items  = (const int*)  d_in[1];
    const int*   neg_items  = (const int*)  d_in[2];
    const float* rpkms      = (const float*)d_in[3];
    const float* user_emb   = (const float*)d_in[4];
    const float* item_emb   = (const float*)d_in[5];
    const float* beta_uD    = (const float*)d_in[6];
    const float* beta_iD    = (const float*)d_in[7];
    const int*   ii_nbr     = (const int*)  d_in[8];
    const float* ii_con     = (const float*)d_in[9];
    const float* mse_u_w    = (const float*)d_in[10];
    const float* mse_u_b    = (const float*)d_in[11];
    const float* mse_i_w    = (const float*)d_in[12];
    const float* mse_i_b    = (const float*)d_in[13];
    const float* fc1_w1     = (const float*)d_in[14];
    const float* fc1_b1     = (const float*)d_in[15];
    const float* fc1_w2     = (const float*)d_in[16];
    const float* fc1_b2     = (const float*)d_in[17];

    float* acc = (float*)d_ws;  // [0]=loss_L sum, [1]=loss_I sum, [2]=norm sum, [3]=mse sum
    hipMemsetAsync(d_ws, 0, 4 * sizeof(float), stream);

    fused_kernel<<<NORMB + GATHB, 256, 0, stream>>>(users, pos_items, neg_items,
                                                    user_emb, item_emb, beta_uD, beta_iD,
                                                    ii_nbr, ii_con,
                                                    mse_u_w, mse_u_b, mse_i_w, mse_i_b,
                                                    fc1_w1, fc1_b1, fc1_w2, fc1_b2, acc);

    mse_kernel<<<BB / 4, 256, 0, stream>>>(users, pos_items, rpkms,
                                           user_emb, item_emb,
                                           mse_u_w, mse_u_b, mse_i_w, mse_i_b, acc);

    finalize_kernel<<<1, 64, 0, stream>>>(acc, (float*)d_out);
}

// Round 4
// 476.808 us; speedup vs baseline: 1.6973x; 1.1146x over previous
//
#include <hip/hip_runtime.h>
#include <math.h>

// Problem constants (match reference)
#define UU 500000
#define II 500000
#define DD 64
#define KK 32
#define BB 8192
#define NNEG 128

typedef float v4f __attribute__((ext_vector_type(4)));

__device__ __forceinline__ float softplus_f(float x) {
    return fmaxf(x, 0.0f) + log1pf(expf(-fabsf(x)));
}

__device__ __forceinline__ float waveReduceSum(float v) {
#pragma unroll
    for (int off = 32; off > 0; off >>= 1) v += __shfl_xor(v, off, 64);
    return v;
}

__device__ __forceinline__ unsigned int bf16pack2(float lo, float hi) {
    // round-to-nearest-even bf16, packed pair (lo in low 16)
    unsigned int ul = __float_as_uint(lo);
    ul += 0x7FFFu + ((ul >> 16) & 1u);
    unsigned int uh = __float_as_uint(hi);
    uh += 0x7FFFu + ((uh >> 16) & 1u);
    return (ul >> 16) | (uh & 0xFFFF0000u);
}

// ===========================================================================
// K1: norm over all params (fp32) + convert item_emb -> bf16 table in d_ws.
// Pure streaming, all CUs. 4096 blocks x 256.
// ===========================================================================
__global__ __launch_bounds__(256) void norm_convert_kernel(
    const float* __restrict__ user_emb, const float* __restrict__ item_emb,
    unsigned int* __restrict__ bfit,    // II*DD bf16 = II*DD/2 uints
    const float* __restrict__ mse_u_w, const float* __restrict__ mse_u_b,
    const float* __restrict__ mse_i_w, const float* __restrict__ mse_i_b,
    const float* __restrict__ fc1_w1, const float* __restrict__ fc1_b1,
    const float* __restrict__ fc1_w2, const float* __restrict__ fc1_b2,
    float* __restrict__ acc)
{
    const size_t tid = (size_t)blockIdx.x * blockDim.x + threadIdx.x;
    const size_t st  = (size_t)gridDim.x * blockDim.x;
    float s = 0.f;

    // ---- item_emb: read fp32 (NT), accumulate squares, write bf16 ----
    {
        const size_t npair = (size_t)II * DD / 8;   // 4M: each iter = 2 float4 -> one uint4
        const v4f* it4 = (const v4f*)item_emb;
        uint4* out4 = (uint4*)bfit;
        for (size_t k = tid; k < npair; k += st) {
            v4f a = __builtin_nontemporal_load(&it4[2 * k]);
            v4f b = __builtin_nontemporal_load(&it4[2 * k + 1]);
            s += a.x*a.x + a.y*a.y + a.z*a.z + a.w*a.w;
            s += b.x*b.x + b.y*b.y + b.z*b.z + b.w*b.w;
            uint4 w;
            w.x = bf16pack2(a.x, a.y);
            w.y = bf16pack2(a.z, a.w);
            w.z = bf16pack2(b.x, b.y);
            w.w = bf16pack2(b.z, b.w);
            out4[k] = w;   // normal store: want it L2/L3 resident for K2
        }
    }
    // ---- user_emb: squares only ----
    {
        const size_t n4 = (size_t)UU * DD / 4;
        const v4f* a = (const v4f*)user_emb;
        for (size_t i = tid; i < n4; i += st) {
            v4f x = __builtin_nontemporal_load(&a[i]);
            s += x.x*x.x + x.y*x.y + x.z*x.z + x.w*x.w;
        }
    }
    // ---- small params ----
    for (size_t i = tid; i < (size_t)DD * DD; i += st)
        s += mse_u_w[i] * mse_u_w[i] + mse_i_w[i] * mse_i_w[i];
    for (size_t i = tid; i < (size_t)DD * 2 * DD; i += st)
        s += fc1_w1[i] * fc1_w1[i];
    for (size_t i = tid; i < (size_t)DD; i += st)
        s += mse_u_b[i] * mse_u_b[i] + mse_i_b[i] * mse_i_b[i]
           + fc1_b1[i] * fc1_b1[i] + fc1_w2[i] * fc1_w2[i];
    if (tid == 0) s += fc1_b2[0] * fc1_b2[0];

    s = waveReduceSum(s);
    __shared__ float red[4];
    if ((threadIdx.x & 63) == 0) red[threadIdx.x >> 6] = s;
    __syncthreads();
    if (threadIdx.x == 0)
        atomicAdd(&acc[2], red[0] + red[1] + red[2] + red[3]);
}

// ===========================================================================
// K2: gather loss_L + loss_I from bf16 table, fused mse. One wave per b.
// 4 lanes per item; bf16 row = 128 B = 2 x 16B loads per lane.
// 10 gather groups (8 neg + 2 nbr), software-pipelined depth 3.
// ===========================================================================
__global__ __launch_bounds__(256) void gather_mse_kernel(
    const int* __restrict__ users, const int* __restrict__ pos_items,
    const int* __restrict__ neg_items, const float* __restrict__ rpkms,
    const float* __restrict__ user_emb, const float* __restrict__ item_emb,
    const unsigned int* __restrict__ bfit,
    const float* __restrict__ beta_uD, const float* __restrict__ beta_iD,
    const int* __restrict__ ii_nbr, const float* __restrict__ ii_con,
    const float* __restrict__ mse_u_w, const float* __restrict__ mse_u_b,
    const float* __restrict__ mse_i_w, const float* __restrict__ mse_i_b,
    float* __restrict__ acc)
{
    const int wave = threadIdx.x >> 6;
    const int lane = threadIdx.x & 63;
    const int b = blockIdx.x * 4 + wave;

    const int u_idx = users[b];
    const int p_idx = pos_items[b];
    const float u_reg = user_emb[(size_t)u_idx * DD + lane];
    const float p_reg = item_emb[(size_t)p_idx * DD + lane];   // pos row in fp32
    const float bu = beta_uD[u_idx];

    __shared__ float sU[4][DD];
    __shared__ float sP[4][DD];
    sU[wave][lane] = u_reg;    // wave-synchronous
    sP[wave][lane] = p_reg;

    const int q  = lane & 3;   // quarter within item
    const int li = lane >> 2;  // item within 16-item group

    // lane's u fragment: dims [q*16, q*16+16)
    float4 uv[4], pv[4];
#pragma unroll
    for (int j = 0; j < 4; ++j) {
        uv[j] = *(const float4*)&sU[wave][q * 16 + j * 4];
        pv[j] = *(const float4*)&sP[wave][q * 16 + j * 4];
    }

    float accL = 0.f, accI = 0.f, accM = 0.f;

    // ---- pos score (fp32) ----
    {
        const float pos_dot = waveReduceSum(u_reg * p_reg);
        if (lane == 0)
            accL += (1e-6f + bu * beta_iD[p_idx]) * softplus_f(-pos_dot);
    }

    // ---- preload indices/weights (lane-resident, broadcast via shfl) ----
    const int i0 = neg_items[(size_t)b * NNEG + lane];
    const int i1 = neg_items[(size_t)b * NNEG + 64 + lane];
    const float bn0 = beta_iD[i0];
    const float bn1 = beta_iD[i1];
    int nbv = 0; float simv = 0.f;
    if (lane < KK) {
        nbv  = ii_nbr[(size_t)p_idx * KK + lane];
        simv = ii_con[(size_t)p_idx * KK + lane];
    }

    const float negscale4 = 0.25f * (200.0f / (float)NNEG);

    // ring buffers for pipelined gather (depth 3)
    uint4 rg[3][2];
    float rw[3];

    // prep(g): resolve idx/weight, issue 2 x 16B loads of bf16 row fragment
#define PREP(g, slot)                                                          \
    {                                                                          \
        int idx; float w;                                                      \
        if ((g) < 4)      { idx = __shfl(i0, (g) * 16 + li, 64);               \
                            w   = __shfl(bn0, (g) * 16 + li, 64); }            \
        else if ((g) < 8) { idx = __shfl(i1, ((g) - 4) * 16 + li, 64);         \
                            w   = __shfl(bn1, ((g) - 4) * 16 + li, 64); }      \
        else              { idx = __shfl(nbv, ((g) - 8) * 16 + li, 64);        \
                            w   = __shfl(simv, ((g) - 8) * 16 + li, 64); }     \
        const uint4* row = (const uint4*)(bfit + (size_t)idx * (DD / 2));      \
        rg[slot][0] = row[q * 2];                                              \
        rg[slot][1] = row[q * 2 + 1];                                          \
        rw[slot] = w;                                                          \
    }

#define DOT8(wv, ua, ub, d)                                                    \
    {                                                                          \
        d = fmaf(__uint_as_float((wv).x << 16), ua.x, d);                      \
        d = fmaf(__uint_as_float((wv).x & 0xFFFF0000u), ua.y, d);              \
        d = fmaf(__uint_as_float((wv).y << 16), ua.z, d);                      \
        d = fmaf(__uint_as_float((wv).y & 0xFFFF0000u), ua.w, d);              \
        d = fmaf(__uint_as_float((wv).z << 16), ub.x, d);                      \
        d = fmaf(__uint_as_float((wv).z & 0xFFFF0000u), ub.y, d);              \
        d = fmaf(__uint_as_float((wv).w << 16), ub.z, d);                      \
        d = fmaf(__uint_as_float((wv).w & 0xFFFF0000u), ub.w, d);              \
    }

#define CONSUME(g, slot)                                                       \
    {                                                                          \
        float dot = 0.f;                                                       \
        DOT8(rg[slot][0], uv[0], uv[1], dot);                                  \
        DOT8(rg[slot][1], uv[2], uv[3], dot);                                  \
        dot += __shfl_xor(dot, 1, 64);                                         \
        dot += __shfl_xor(dot, 2, 64);                                         \
        if ((g) < 8) accL += negscale4 * (1e-6f + bu * rw[slot]) * softplus_f(dot); \
        else         accI += 0.25f * rw[slot] * softplus_f(-dot);              \
    }

    PREP(0, 0); PREP(1, 1); PREP(2, 2);
    CONSUME(0, 0); PREP(3, 0);
    CONSUME(1, 1); PREP(4, 1);
    CONSUME(2, 2); PREP(5, 2);
    CONSUME(3, 0); PREP(6, 0);
    CONSUME(4, 1); PREP(7, 1);
    CONSUME(5, 2); PREP(8, 2);
    CONSUME(6, 0); PREP(9, 0);
    CONSUME(7, 1);
    CONSUME(8, 2);
    CONSUME(9, 0);
#undef PREP
#undef DOT8
#undef CONSUME

    // ---- fused mse: feat_u = Wu@u + bu_, feat_i = Wi@p + bi_, pred = <fu,fi> ----
    {
        float pq = 0.f;
#pragma unroll
        for (int g = 0; g < 4; ++g) {
            const int r = g * 16 + li;
            const float* wur = mse_u_w + r * DD + q * 16;
            const float* wir = mse_i_w + r * DD + q * 16;
            float fu = 0.f, fi = 0.f;
#pragma unroll
            for (int j = 0; j < 4; ++j) {
                const float4 a = *(const float4*)(wur + j * 4);
                fu = fmaf(a.x, uv[j].x, fu); fu = fmaf(a.y, uv[j].y, fu);
                fu = fmaf(a.z, uv[j].z, fu); fu = fmaf(a.w, uv[j].w, fu);
                const float4 c = *(const float4*)(wir + j * 4);
                fi = fmaf(c.x, pv[j].x, fi); fi = fmaf(c.y, pv[j].y, fi);
                fi = fmaf(c.z, pv[j].z, fi); fi = fmaf(c.w, pv[j].w, fi);
            }
            fu += __shfl_xor(fu, 1, 64); fu += __shfl_xor(fu, 2, 64);
            fi += __shfl_xor(fi, 1, 64); fi += __shfl_xor(fi, 2, 64);
            fu += mse_u_b[r];
            fi += mse_i_b[r];
            pq += fu * fi;
        }
        const float pred = waveReduceSum(pq) * 0.25f;   // 4-lane redundancy
        if (lane == 0) {
            const float diff = pred - rpkms[b];
            accM += diff * diff;
        }
    }

    // ---- block reduce + one atomic set per block ----
    accL = waveReduceSum(accL);
    accI = waveReduceSum(accI);
    __shared__ float redL[4], redI[4], redM[4];
    if (lane == 0) { redL[wave] = accL; redI[wave] = accI; redM[wave] = accM; }
    __syncthreads();
    if (threadIdx.x == 0) {
        atomicAdd(&acc[0], redL[0] + redL[1] + redL[2] + redL[3]);
        atomicAdd(&acc[1], redI[0] + redI[1] + redI[2] + redI[3]);
        atomicAdd(&acc[3], redM[0] + redM[1] + redM[2] + redM[3]);
    }
}

// ===========================================================================
// Fallback (ws too small for bf16 table): R2's verified fp32 path
// ===========================================================================
#define NORMB 1024
__global__ __launch_bounds__(256) void fb_fused_kernel(
    const int* __restrict__ users, const int* __restrict__ pos_items,
    const int* __restrict__ neg_items,
    const float* __restrict__ user_emb, const float* __restrict__ item_emb,
    const float* __restrict__ beta_uD, const float* __restrict__ beta_iD,
    const int* __restrict__ ii_nbr, const float* __restrict__ ii_con,
    const float* __restrict__ mse_u_w, const float* __restrict__ mse_u_b,
    const float* __restrict__ mse_i_w, const float* __restrict__ mse_i_b,
    const float* __restrict__ fc1_w1, const float* __restrict__ fc1_b1,
    const float* __restrict__ fc1_w2, const float* __restrict__ fc1_b2,
    float* __restrict__ acc)
{
    const int wave = threadIdx.x >> 6;
    const int lane = threadIdx.x & 63;
    __shared__ float red[4];

    if (blockIdx.x < NORMB) {
        const size_t tid = (size_t)blockIdx.x * blockDim.x + threadIdx.x;
        const size_t st  = (size_t)NORMB * 256;
        const size_t n4  = (size_t)UU * DD / 4;
        float s = 0.f;
        const v4f* a = (const v4f*)user_emb;
        for (size_t i = tid; i < n4; i += st) {
            v4f x = a[i]; s += x.x*x.x + x.y*x.y + x.z*x.z + x.w*x.w;
        }
        const v4f* c = (const v4f*)item_emb;
        for (size_t i = tid; i < n4; i += st) {
            v4f x = c[i]; s += x.x*x.x + x.y*x.y + x.z*x.z + x.w*x.w;
        }
        for (size_t i = tid; i < (size_t)DD * DD; i += st)
            s += mse_u_w[i] * mse_u_w[i] + mse_i_w[i] * mse_i_w[i];
        for (size_t i = tid; i < (size_t)DD * 2 * DD; i += st)
            s += fc1_w1[i] * fc1_w1[i];
        for (size_t i = tid; i < (size_t)DD; i += st)
            s += mse_u_b[i] * mse_u_b[i] + mse_i_b[i] * mse_i_b[i]
               + fc1_b1[i] * fc1_b1[i] + fc1_w2[i] * fc1_w2[i];
        if (tid == 0) s += fc1_b2[0] * fc1_b2[0];
        s = waveReduceSum(s);
        if (lane == 0) red[wave] = s;
        __syncthreads();
        if (threadIdx.x == 0)
            atomicAdd(&acc[2], red[0] + red[1] + red[2] + red[3]);
        return;
    }

    const int b = (blockIdx.x - NORMB) * 4 + wave;
    float accL = 0.f, accI = 0.f;
    const int u_idx = users[b];
    const int p_idx = pos_items[b];
    const float u_reg = user_emb[(size_t)u_idx * DD + lane];
    const float bu = beta_uD[u_idx];
    __shared__ float sU[4][DD];
    sU[wave][lane] = u_reg;
    const int q  = lane & 3;
    const int li = lane >> 2;
    float4 uv[4];
#pragma unroll
    for (int j = 0; j < 4; ++j) uv[j] = *(const float4*)&sU[wave][j * 16 + q * 4];
    {
        const float p = item_emb[(size_t)p_idx * DD + lane];
        const float pos_dot = waveReduceSum(u_reg * p);
        if (lane == 0) accL += (1e-6f + bu * beta_iD[p_idx]) * softplus_f(-pos_dot);
    }
    const int i0 = neg_items[(size_t)b * NNEG + lane];
    const int i1 = neg_items[(size_t)b * NNEG + 64 + lane];
    const float bn0 = beta_iD[i0];
    const float bn1 = beta_iD[i1];
    const float negscale4 = 0.25f * (200.0f / (float)NNEG);
#pragma unroll
    for (int g = 0; g < 2; ++g) {
        const int   srcI = g ? i1 : i0;
        const float srcB = g ? bn1 : bn0;
        float4 vb[4][4]; float bi4[4];
#pragma unroll
        for (int t = 0; t < 4; ++t) {
            const int n = t * 16 + li;
            const int idx = __shfl(srcI, n, 64);
            bi4[t] = __shfl(srcB, n, 64);
            const float* row = item_emb + (size_t)idx * DD + q * 4;
#pragma unroll
            for (int j = 0; j < 4; ++j) vb[t][j] = *(const float4*)(row + j * 16);
        }
#pragma unroll
        for (int t = 0; t < 4; ++t) {
            float dot = 0.f;
#pragma unroll
            for (int j = 0; j < 4; ++j) {
                dot = fmaf(vb[t][j].x, uv[j].x, dot);
                dot = fmaf(vb[t][j].y, uv[j].y, dot);
                dot = fmaf(vb[t][j].z, uv[j].z, dot);
                dot = fmaf(vb[t][j].w, uv[j].w, dot);
            }
            dot += __shfl_xor(dot, 1, 64);
            dot += __shfl_xor(dot, 2, 64);
            accL += negscale4 * (1e-6f + bu * bi4[t]) * softplus_f(dot);
        }
    }
    int nbv = 0; float simv = 0.f;
    if (lane < KK) {
        nbv  = ii_nbr[(size_t)p_idx * KK + lane];
        simv = ii_con[(size_t)p_idx * KK + lane];
    }
    {
        float4 vb[2][4]; float sk2[2];
#pragma unroll
        for (int t = 0; t < 2; ++t) {
            const int n = t * 16 + li;
            const int idx = __shfl(nbv, n, 64);
            sk2[t] = __shfl(simv, n, 64);
            const float* row = item_emb + (size_t)idx * DD + q * 4;
#pragma unroll
            for (int j = 0; j < 4; ++j) vb[t][j] = *(const float4*)(row + j * 16);
        }
#pragma unroll
        for (int t = 0; t < 2; ++t) {
            float dot = 0.f;
#pragma unroll
            for (int j = 0; j < 4; ++j) {
                dot = fmaf(vb[t][j].x, uv[j].x, dot);
                dot = fmaf(vb[t][j].y, uv[j].y, dot);
                dot = fmaf(vb[t][j].z, uv[j].z, dot);
                dot = fmaf(vb[t][j].w, uv[j].w, dot);
            }
            dot += __shfl_xor(dot, 1, 64);
            dot += __shfl_xor(dot, 2, 64);
            accI += 0.25f * sk2[t] * softplus_f(-dot);
        }
    }
    accL = waveReduceSum(accL);
    accI = waveReduceSum(accI);
    __shared__ float redL[4], redI[4];
    if (lane == 0) { redL[wave] = accL; redI[wave] = accI; }
    __syncthreads();
    if (threadIdx.x == 0) {
        atomicAdd(&acc[0], redL[0] + redL[1] + redL[2] + redL[3]);
        atomicAdd(&acc[1], redI[0] + redI[1] + redI[2] + redI[3]);
    }
}

__global__ __launch_bounds__(256) void fb_mse_kernel(
    const int* __restrict__ users, const int* __restrict__ pos_items,
    const float* __restrict__ rpkms,
    const float* __restrict__ user_emb, const float* __restrict__ item_emb,
    const float* __restrict__ mse_u_w, const float* __restrict__ mse_u_b,
    const float* __restrict__ mse_i_w, const float* __restrict__ mse_i_b,
    float* __restrict__ acc)
{
    __shared__ float sWu[DD * (DD + 1)];
    __shared__ float sWi[DD * (DD + 1)];
    __shared__ float sBu[DD], sBi[DD];
    __shared__ float sUe[4][DD], sPe[4][DD];
    for (int i = threadIdx.x; i < DD * DD; i += blockDim.x) {
        const int r = i >> 6, c = i & 63;
        sWu[r * (DD + 1) + c] = mse_u_w[i];
        sWi[r * (DD + 1) + c] = mse_i_w[i];
    }
    if (threadIdx.x < DD) {
        sBu[threadIdx.x] = mse_u_b[threadIdx.x];
        sBi[threadIdx.x] = mse_i_b[threadIdx.x];
    }
    const int wave = threadIdx.x >> 6;
    const int lane = threadIdx.x & 63;
    const int b = blockIdx.x * 4 + wave;
    sUe[wave][lane] = user_emb[(size_t)users[b] * DD + lane];
    sPe[wave][lane] = item_emb[(size_t)pos_items[b] * DD + lane];
    __syncthreads();
    float fu = sBu[lane];
    float fi = sBi[lane];
#pragma unroll 8
    for (int d = 0; d < DD; ++d) {
        fu += sUe[wave][d] * sWu[lane * (DD + 1) + d];
        fi += sPe[wave][d] * sWi[lane * (DD + 1) + d];
    }
    const float pred = waveReduceSum(fu * fi);
    if (lane == 0) {
        const float diff = pred - rpkms[b];
        atomicAdd(&acc[3], diff * diff);
    }
}

// ---------------- finalize ----------------
__global__ void finalize_kernel(const float* __restrict__ acc, float* __restrict__ out)
{
    if (threadIdx.x == 0) {
        const float loss_L = acc[0] / (float)BB;
        const float loss_I = 2.5f * acc[1] / (float)(BB * KK);
        const float mse    = acc[3] / (float)BB;
        const float norm   = 1e-4f * 0.5f * acc[2];
        const float total  = loss_L + norm + loss_I + mse;
        out[0] = total;
        out[1] = loss_L;
        out[2] = loss_I;
        out[3] = 0.0f;
        out[4] = mse;
        out[5] = norm;
    }
}

extern "C" void kernel_launch(void* const* d_in, const int* in_sizes, int n_in,
                              void* d_out, int out_size, void* d_ws, size_t ws_size,
                              hipStream_t stream)
{
    const int*   users      = (const int*)  d_in[0];
    const int*   pos_items  = (const int*)  d_in[1];
    const int*   neg_items  = (const int*)  d_in[2];
    const float* rpkms      = (const float*)d_in[3];
    const float* user_emb   = (const float*)d_in[4];
    const float* item_emb   = (const float*)d_in[5];
    const float* beta_uD    = (const float*)d_in[6];
    const float* beta_iD    = (const float*)d_in[7];
    const int*   ii_nbr     = (const int*)  d_in[8];
    const float* ii_con     = (const float*)d_in[9];
    const float* mse_u_w    = (const float*)d_in[10];
    const float* mse_u_b    = (const float*)d_in[11];
    const float* mse_i_w    = (const float*)d_in[12];
    const float* mse_i_b    = (const float*)d_in[13];
    const float* fc1_w1     = (const float*)d_in[14];
    const float* fc1_b1     = (const float*)d_in[15];
    const float* fc1_w2     = (const float*)d_in[16];
    const float* fc1_b2     = (const float*)d_in[17];

    float* acc = (float*)d_ws;  // [0]=loss_L, [1]=loss_I, [2]=norm, [3]=mse (sums)
    hipMemsetAsync(d_ws, 0, 4 * sizeof(float), stream);

    const size_t bf_bytes = (size_t)II * DD * 2;   // 64 MB bf16 table
    const size_t need = 256 + bf_bytes;

    if (ws_size >= need) {
        unsigned int* bfit = (unsigned int*)((char*)d_ws + 256);
        norm_convert_kernel<<<4096, 256, 0, stream>>>(
            user_emb, item_emb, bfit,
            mse_u_w, mse_u_b, mse_i_w, mse_i_b,
            fc1_w1, fc1_b1, fc1_w2, fc1_b2, acc);
        gather_mse_kernel<<<BB / 4, 256, 0, stream>>>(
            users, pos_items, neg_items, rpkms,
            user_emb, item_emb, bfit, beta_uD, beta_iD,
            ii_nbr, ii_con, mse_u_w, mse_u_b, mse_i_w, mse_i_b, acc);
    } else {
        fb_fused_kernel<<<NORMB + BB / 4, 256, 0, stream>>>(
            users, pos_items, neg_items,
            user_emb, item_emb, beta_uD, beta_iD, ii_nbr, ii_con,
            mse_u_w, mse_u_b, mse_i_w, mse_i_b,
            fc1_w1, fc1_b1, fc1_w2, fc1_b2, acc);
        fb_mse_kernel<<<BB / 4, 256, 0, stream>>>(
            users, pos_items, rpkms, user_emb, item_emb,
            mse_u_w, mse_u_b, mse_i_w, mse_i_b, acc);
    }

    finalize_kernel<<<1, 64, 0, stream>>>(acc, (float*)d_out);
}